// Round 14
// baseline (159.603 us; speedup 1.0000x reference)
//
#include <hip/hip_runtime.h>

#define B_  8
#define TQ  256
#define TV  512
#define DD  256
#define ALGS 520  // alg row stride: write banks <=2-way aliased = free

__device__ __forceinline__ float fast_exp2(float x) {
#if __has_builtin(__builtin_amdgcn_exp2f)
  return __builtin_amdgcn_exp2f(x);
#else
  return __exp2f(x);
#endif
}
__device__ __forceinline__ float fast_rcp(float x) {
#if __has_builtin(__builtin_amdgcn_rcpf)
  return __builtin_amdgcn_rcpf(x);
#else
  return 1.0f / x;
#endif
}

// ---------------------------------------------------------------------------
// Fused projections with EXP epilogue (identical to rounds 8-13 — validated):
//   Eq = exp2(SC*(query@W1 + b1)),  Ev = exp2(SC*(value@W2 + b2))
// ---------------------------------------------------------------------------
__global__ __launch_bounds__(256) void proj_fused(
    const float* __restrict__ query, const float* __restrict__ value,
    const float* __restrict__ W1, const float* __restrict__ b1,
    const float* __restrict__ W2, const float* __restrict__ b2,
    float* __restrict__ qp, float* __restrict__ vp, float scale) {
  __shared__ float As[2][32][64];  // [p][k][m ^ sw(k)]
  __shared__ float Bs[2][32][64];  // [p][k][n]
  const int t  = threadIdx.x;
  const int rt = blockIdx.x;
  const int bn = blockIdx.y << 6;

  const float* A; const float* W; const float* bias; float* out; int row0;
  if (rt < 32) { row0 = rt << 6;        A = query; W = W1; bias = b1; out = qp; }
  else         { row0 = (rt - 32) << 6; A = value; W = W2; bias = b2; out = vp; }

  const int tx = t & 15, ty = t >> 4;
  const int aar = t >> 3, aac = (t & 7) << 2;
  const int bbr = t >> 4, bbc = (t & 15) << 2;

  float4 ra[2], rb[2];
#pragma unroll
  for (int it = 0; it < 2; ++it) {
    ra[it] = *(const float4*)(A + (size_t)(row0 + (it << 5) + aar) * DD + aac);
    rb[it] = *(const float4*)(W + (size_t)((it << 4) + bbr) * DD + bn + bbc);
  }
#pragma unroll
  for (int it = 0; it < 2; ++it) {
    const int m = (it << 5) + aar;
#pragma unroll
    for (int c = 0; c < 4; ++c) {
      const int k = aac + c;
      As[0][k][m ^ (((k >> 2) & 7) << 2)] = (&ra[it].x)[c];
    }
    *(float4*)&Bs[0][(it << 4) + bbr][bbc] = rb[it];
  }
  __syncthreads();

  float acc[4][4] = {{0.f,0.f,0.f,0.f},{0.f,0.f,0.f,0.f},
                     {0.f,0.f,0.f,0.f},{0.f,0.f,0.f,0.f}};
  int p = 0;

  for (int k0 = 0; k0 < 256; k0 += 32) {
    const bool more = (k0 + 32) < 256;
    if (more) {
#pragma unroll
      for (int it = 0; it < 2; ++it) {
        ra[it] = *(const float4*)(A + (size_t)(row0 + (it << 5) + aar) * DD + k0 + 32 + aac);
        rb[it] = *(const float4*)(W + (size_t)(k0 + 32 + (it << 4) + bbr) * DD + bn + bbc);
      }
    }
#pragma unroll
    for (int k = 0; k < 32; ++k) {
      float4 aq = *(const float4*)&As[p][k][(ty << 2) ^ (((k >> 2) & 7) << 2)];
      float4 bq = *(const float4*)&Bs[p][k][tx << 2];
      acc[0][0] = fmaf(aq.x, bq.x, acc[0][0]); acc[0][1] = fmaf(aq.x, bq.y, acc[0][1]);
      acc[0][2] = fmaf(aq.x, bq.z, acc[0][2]); acc[0][3] = fmaf(aq.x, bq.w, acc[0][3]);
      acc[1][0] = fmaf(aq.y, bq.x, acc[1][0]); acc[1][1] = fmaf(aq.y, bq.y, acc[1][1]);
      acc[1][2] = fmaf(aq.y, bq.z, acc[1][2]); acc[1][3] = fmaf(aq.y, bq.w, acc[1][3]);
      acc[2][0] = fmaf(aq.z, bq.x, acc[2][0]); acc[2][1] = fmaf(aq.z, bq.y, acc[2][1]);
      acc[2][2] = fmaf(aq.z, bq.z, acc[2][2]); acc[2][3] = fmaf(aq.z, bq.w, acc[2][3]);
      acc[3][0] = fmaf(aq.w, bq.x, acc[3][0]); acc[3][1] = fmaf(aq.w, bq.y, acc[3][1]);
      acc[3][2] = fmaf(aq.w, bq.z, acc[3][2]); acc[3][3] = fmaf(aq.w, bq.w, acc[3][3]);
    }
    if (more) {
      const int q = p ^ 1;
#pragma unroll
      for (int it = 0; it < 2; ++it) {
        const int m = (it << 5) + aar;
#pragma unroll
        for (int c = 0; c < 4; ++c) {
          const int k = aac + c;
          As[q][k][m ^ (((k >> 2) & 7) << 2)] = (&ra[it].x)[c];
        }
        *(float4*)&Bs[q][(it << 4) + bbr][bbc] = rb[it];
      }
      __syncthreads();
      p = q;
    }
  }

  float4 bvv = *(const float4*)&bias[bn + (tx << 2)];
#pragma unroll
  for (int r = 0; r < 4; ++r) {
    float4 o;
    o.x = fast_exp2(scale * (acc[r][0] + bvv.x));
    o.y = fast_exp2(scale * (acc[r][1] + bvv.y));
    o.z = fast_exp2(scale * (acc[r][2] + bvv.z));
    o.w = fast_exp2(scale * (acc[r][3] + bvv.w));
    *(float4*)(out + (size_t)(row0 + (ty << 2) + r) * DD + bn + (tx << 2)) = o;
  }
}

// ---------------------------------------------------------------------------
// Fused score + softmax + context + concat + transposed alignment.
// 512 blocks x 1024 THREADS (16 waves), 4 q-rows per block, TI=4.
// 2 blocks/CU x 16 waves = 32 waves/CU = FULL occupancy (round 13 had 16).
// Same L2 traffic as round 13 (each block reads its Ev+value slab once).
// Wave wv (0..15) owns j-rows jb = wv*16 + jj for jg in {0,1} (j = jb+256jg);
// lane = (jj = lane>>2, dq = lane&3). acc[4 rows][2 jg] in VGPRs; software
// pipeline prefetches k+1's 2 Ev quads (global) + 4 Eq quads (LDS).
// One 2-step quad butterfly at the end; lane writes the i = dq slice.
// __launch_bounds__(1024, 8) -> VGPR cap 64 (est. ~50 live; WRITE_SIZE is
// the spill tripwire). LDS 20.6 KB.
// Math (Eq,Ev; x = Eq*Ev): quad-rcp; score = 256 - 2*S; min-S softmax.
// ---------------------------------------------------------------------------
__global__ __launch_bounds__(1024, 8) void attn_kernel(
    const float* __restrict__ qp, const float* __restrict__ vp,
    const float* __restrict__ value, const float* __restrict__ query,
    float* __restrict__ out1, float* __restrict__ out2) {
  __shared__ float qs[4 * 256];    // Eq rows, 4 KB
  __shared__ float alg[4 * ALGS];  // raw S then alignment, 8.3 KB
  __shared__ float part[2048];     // context partials, 8 KB

  const int t    = threadIdx.x;
  const int lane = t & 63;
  const int wv   = t >> 6;        // 0..15
  const int jj   = lane >> 2;     // 0..15
  const int dq   = lane & 3;      // d-quarter phase
  const int bb   = blockIdx.x & 7;          // batch -> XCD locality
  const int i0   = (blockIdx.x >> 3) << 2;  // first of 4 q-rows

  const float* vpb = vp + (size_t)bb * TV * DD;
  const float* qb  = qp + (size_t)(bb * TQ + i0) * DD;

  // stage 4 Eq rows into LDS (coalesced)
  if (t < 256) {
    const int qi = t >> 6, qc = (t & 63) << 2;
    *(float4*)&qs[qi * 256 + qc] = *(const float4*)(qb + (size_t)qi * DD + qc);
  }
  __syncthreads();

  // per-lane Ev row bases: j(jg) = jg*256 + wv*16 + jj
  const int jb = (wv << 4) + jj;       // 0..255
  const float* vr0 = vpb + (size_t)jb * DD + (dq << 2);
  const float* vr1 = vr0 + 256 * DD;
  const float* qlane = qs + (dq << 2);

  float acc[4][2] = {{0.f,0.f},{0.f,0.f},{0.f,0.f},{0.f,0.f}};

  // prime the pipeline: k = 0 operands
  float4 vn0 = *(const float4*)(vr0);
  float4 vn1 = *(const float4*)(vr1);
  float4 qn0 = *(const float4*)(qlane + 0 * 256);
  float4 qn1 = *(const float4*)(qlane + 1 * 256);
  float4 qn2 = *(const float4*)(qlane + 2 * 256);
  float4 qn3 = *(const float4*)(qlane + 3 * 256);

#pragma unroll 1
  for (int k = 0; k < 16; ++k) {
    float4 vc0 = vn0, vc1 = vn1;
    float4 q0 = qn0, q1 = qn1, q2 = qn2, q3 = qn3;
    if (k < 15) {  // issue k+1 loads BEFORE computing k
      const int dn = (k + 1) << 4;
      vn0 = *(const float4*)(vr0 + dn);
      vn1 = *(const float4*)(vr1 + dn);
      qn0 = *(const float4*)(qlane + 0 * 256 + dn);
      qn1 = *(const float4*)(qlane + 1 * 256 + dn);
      qn2 = *(const float4*)(qlane + 2 * 256 + dn);
      qn3 = *(const float4*)(qlane + 3 * 256 + dn);
    }
#pragma unroll
    for (int jg = 0; jg < 2; ++jg) {
      const float4 v4 = (jg == 0) ? vc0 : vc1;
#pragma unroll
      for (int i = 0; i < 4; ++i) {
        const float4 q4 = (i == 0) ? q0 : (i == 1) ? q1 : (i == 2) ? q2 : q3;
        float a = q4.x * v4.x, b = q4.y * v4.y;
        float c = q4.z * v4.z, d = q4.w * v4.w;
        float sab = a + b,  scd = c + d;
        float Q1 = fmaf(a, b, sab + 1.f);   // (1+a)(1+b)
        float Q2 = fmaf(c, d, scd + 1.f);   // (1+c)(1+d)
        float N  = fmaf(scd + 2.f, Q1, (sab + 2.f) * Q2);
        acc[i][jg] = fmaf(N, fast_rcp(Q1 * Q2), acc[i][jg]);
      }
    }
  }

  // quad butterfly (once): combine the 4 d-quarter partials within each jj
#pragma unroll
  for (int i = 0; i < 4; ++i)
#pragma unroll
    for (int jg = 0; jg < 2; ++jg) {
      acc[i][jg] += __shfl_xor(acc[i][jg], 1, 64);
      acc[i][jg] += __shfl_xor(acc[i][jg], 2, 64);
    }
  // lane writes the i = dq slice (banks <=2-way = free)
#pragma unroll
  for (int jg = 0; jg < 2; ++jg) {
    float x = (dq == 0) ? acc[0][jg] : (dq == 1) ? acc[1][jg]
            : (dq == 2) ? acc[2][jg] : acc[3][jg];
    alg[dq * ALGS + (jg << 8) + jb] = x;
  }
  __syncthreads();

  // ---- softmax over j: wave wv (<4) owns row wv exclusively ----
  // score = 256 - 2*S -> max(score) <-> min(S); w = exp2(CC*(Smin - S))
  if (wv < 4) {
    float s[8];
#pragma unroll
    for (int c = 0; c < 8; ++c) s[c] = alg[wv * ALGS + (c << 6) + lane];
    float mn = s[0];
#pragma unroll
    for (int c = 1; c < 8; ++c) mn = fminf(mn, s[c]);
#pragma unroll
    for (int m = 1; m < 64; m <<= 1) mn = fminf(mn, __shfl_xor(mn, m, 64));

    const float CC = 2.8853900817779268f;  // 2*log2(e)
    float p[8];
    float sum = 0.f;
#pragma unroll
    for (int c = 0; c < 8; ++c) { p[c] = fast_exp2(CC * (mn - s[c])); sum += p[c]; }
#pragma unroll
    for (int m = 1; m < 64; m <<= 1) sum += __shfl_xor(sum, m, 64);
    const float inv = fast_rcp(sum);
#pragma unroll
    for (int c = 0; c < 8; ++c) alg[wv * ALGS + (c << 6) + lane] = p[c] * inv;
  }
  __syncthreads();

  // ---- alignment_t write: out2[b][j][i0..i0+3], threads 0..511 ----
  if (t < 512) {
    const int j = t;
    float4 av = make_float4(alg[j], alg[ALGS + j], alg[2 * ALGS + j], alg[3 * ALGS + j]);
    *(float4*)(out2 + (size_t)(bb * TV + j) * TQ + i0) = av;
  }

  // ---- context: thread (f = t&255, rp = (t>>8)&1, jh = t>>9) ----
  const int f  = t & 255;
  const int rp = (t >> 8) & 1;    // row-pair: rows 2rp, 2rp+1
  const int jh = t >> 9;          // j-half: [jh*256, jh*256+256)
  float c0 = 0.f, c1 = 0.f;
  const float* vb = value + (size_t)bb * TV * DD;
  const float* a0p = &alg[(2 * rp + 0) * ALGS];
  const float* a1p = &alg[(2 * rp + 1) * ALGS];
  const int jbeg = jh << 8;
#pragma unroll 4
  for (int j = jbeg; j < jbeg + 256; j += 4) {
    float v0 = vb[(size_t)(j + 0) * DD + f];
    float v1 = vb[(size_t)(j + 1) * DD + f];
    float v2 = vb[(size_t)(j + 2) * DD + f];
    float v3 = vb[(size_t)(j + 3) * DD + f];
    float4 a0 = *(const float4*)&a0p[j];
    float4 a1 = *(const float4*)&a1p[j];
    c0 += a0.x * v0 + a0.y * v1 + a0.z * v2 + a0.w * v3;
    c1 += a1.x * v0 + a1.y * v1 + a1.z * v2 + a1.w * v3;
  }
  part[(jh << 10) + (rp << 9) + f]       = c0;  // [jh][rp][row 2rp  ][f]
  part[(jh << 10) + (rp << 9) + 256 + f] = c1;  // [jh][rp][row 2rp+1][f]
  __syncthreads();

  // ---- combine halves + write [ctx | query]: thread -> (row = t>>8, f) ----
  {
    const int row = t >> 8;  // 0..3
    const int rpp = row >> 1, rw = row & 1;
    const float cfull = part[(rpp << 9) + (rw << 8) + f]
                      + part[1024 + (rpp << 9) + (rw << 8) + f];
    const float* qg = query + (size_t)(bb * TQ + i0) * DD;
    float* o = out1 + (size_t)(bb * TQ + i0) * (2 * DD);
    o[row * 512 + f]       = cfull;
    o[row * 512 + 256 + f] = qg[row * DD + f];
  }
}

// ---------------------------------------------------------------------------
extern "C" void kernel_launch(void* const* d_in, const int* in_sizes, int n_in,
                              void* d_out, int out_size, void* d_ws, size_t ws_size,
                              hipStream_t stream) {
  const float* query = (const float*)d_in[0];  // [8,256,256]
  const float* value = (const float*)d_in[1];  // [8,512,256]
  const float* W1    = (const float*)d_in[2];  // [256,256]
  const float* b1    = (const float*)d_in[3];  // [256]
  const float* W2    = (const float*)d_in[4];  // [256,256]
  const float* b2    = (const float*)d_in[5];  // [256]

  float* out1 = (float*)d_out;                     // context concat [8,256,512]
  float* out2 = out1 + (size_t)B_ * TQ * 2 * DD;   // alignment_t   [8,512,256]

  float* qp = (float*)d_ws;                        // Eq: 2048*256 floats
  float* vp = qp + (size_t)B_ * TQ * DD;           // Ev: 4096*256 floats

  const float SC = 2.8853900817779268f;  // 2*log2(e): exp(2x) = exp2(SC*x)

  proj_fused<<<dim3(96, 4), 256, 0, stream>>>(query, value, W1, b1, W2, b2, qp, vp, SC);
  attn_kernel<<<dim3(B_ * (TQ / 4)), 1024, 0, stream>>>(qp, vp, value, query, out1, out2);
}

// Round 15
// 141.545 us; speedup vs baseline: 1.1276x; 1.1276x over previous
//
#include <hip/hip_runtime.h>

#define B_  8
#define TQ  256
#define TV  512
#define DD  256
#define ALGS 520  // alg row stride: write banks <=2-way aliased = free

__device__ __forceinline__ float fast_exp2(float x) {
#if __has_builtin(__builtin_amdgcn_exp2f)
  return __builtin_amdgcn_exp2f(x);
#else
  return __exp2f(x);
#endif
}
__device__ __forceinline__ float fast_rcp(float x) {
#if __has_builtin(__builtin_amdgcn_rcpf)
  return __builtin_amdgcn_rcpf(x);
#else
  return 1.0f / x;
#endif
}

// ---------------------------------------------------------------------------
// Fused projections with EXP epilogue (identical to rounds 8-14 — validated):
//   Eq = exp2(SC*(query@W1 + b1)),  Ev = exp2(SC*(value@W2 + b2))
// ---------------------------------------------------------------------------
__global__ __launch_bounds__(256) void proj_fused(
    const float* __restrict__ query, const float* __restrict__ value,
    const float* __restrict__ W1, const float* __restrict__ b1,
    const float* __restrict__ W2, const float* __restrict__ b2,
    float* __restrict__ qp, float* __restrict__ vp, float scale) {
  __shared__ float As[2][32][64];  // [p][k][m ^ sw(k)]
  __shared__ float Bs[2][32][64];  // [p][k][n]
  const int t  = threadIdx.x;
  const int rt = blockIdx.x;
  const int bn = blockIdx.y << 6;

  const float* A; const float* W; const float* bias; float* out; int row0;
  if (rt < 32) { row0 = rt << 6;        A = query; W = W1; bias = b1; out = qp; }
  else         { row0 = (rt - 32) << 6; A = value; W = W2; bias = b2; out = vp; }

  const int tx = t & 15, ty = t >> 4;
  const int aar = t >> 3, aac = (t & 7) << 2;
  const int bbr = t >> 4, bbc = (t & 15) << 2;

  float4 ra[2], rb[2];
#pragma unroll
  for (int it = 0; it < 2; ++it) {
    ra[it] = *(const float4*)(A + (size_t)(row0 + (it << 5) + aar) * DD + aac);
    rb[it] = *(const float4*)(W + (size_t)((it << 4) + bbr) * DD + bn + bbc);
  }
#pragma unroll
  for (int it = 0; it < 2; ++it) {
    const int m = (it << 5) + aar;
#pragma unroll
    for (int c = 0; c < 4; ++c) {
      const int k = aac + c;
      As[0][k][m ^ (((k >> 2) & 7) << 2)] = (&ra[it].x)[c];
    }
    *(float4*)&Bs[0][(it << 4) + bbr][bbc] = rb[it];
  }
  __syncthreads();

  float acc[4][4] = {{0.f,0.f,0.f,0.f},{0.f,0.f,0.f,0.f},
                     {0.f,0.f,0.f,0.f},{0.f,0.f,0.f,0.f}};
  int p = 0;

  for (int k0 = 0; k0 < 256; k0 += 32) {
    const bool more = (k0 + 32) < 256;
    if (more) {
#pragma unroll
      for (int it = 0; it < 2; ++it) {
        ra[it] = *(const float4*)(A + (size_t)(row0 + (it << 5) + aar) * DD + k0 + 32 + aac);
        rb[it] = *(const float4*)(W + (size_t)(k0 + 32 + (it << 4) + bbr) * DD + bn + bbc);
      }
    }
#pragma unroll
    for (int k = 0; k < 32; ++k) {
      float4 aq = *(const float4*)&As[p][k][(ty << 2) ^ (((k >> 2) & 7) << 2)];
      float4 bq = *(const float4*)&Bs[p][k][tx << 2];
      acc[0][0] = fmaf(aq.x, bq.x, acc[0][0]); acc[0][1] = fmaf(aq.x, bq.y, acc[0][1]);
      acc[0][2] = fmaf(aq.x, bq.z, acc[0][2]); acc[0][3] = fmaf(aq.x, bq.w, acc[0][3]);
      acc[1][0] = fmaf(aq.y, bq.x, acc[1][0]); acc[1][1] = fmaf(aq.y, bq.y, acc[1][1]);
      acc[1][2] = fmaf(aq.y, bq.z, acc[1][2]); acc[1][3] = fmaf(aq.y, bq.w, acc[1][3]);
      acc[2][0] = fmaf(aq.z, bq.x, acc[2][0]); acc[2][1] = fmaf(aq.z, bq.y, acc[2][1]);
      acc[2][2] = fmaf(aq.z, bq.z, acc[2][2]); acc[2][3] = fmaf(aq.z, bq.w, acc[2][3]);
      acc[3][0] = fmaf(aq.w, bq.x, acc[3][0]); acc[3][1] = fmaf(aq.w, bq.y, acc[3][1]);
      acc[3][2] = fmaf(aq.w, bq.z, acc[3][2]); acc[3][3] = fmaf(aq.w, bq.w, acc[3][3]);
    }
    if (more) {
      const int q = p ^ 1;
#pragma unroll
      for (int it = 0; it < 2; ++it) {
        const int m = (it << 5) + aar;
#pragma unroll
        for (int c = 0; c < 4; ++c) {
          const int k = aac + c;
          As[q][k][m ^ (((k >> 2) & 7) << 2)] = (&ra[it].x)[c];
        }
        *(float4*)&Bs[q][(it << 4) + bbr][bbc] = rb[it];
      }
      __syncthreads();
      p = q;
    }
  }

  float4 bvv = *(const float4*)&bias[bn + (tx << 2)];
#pragma unroll
  for (int r = 0; r < 4; ++r) {
    float4 o;
    o.x = fast_exp2(scale * (acc[r][0] + bvv.x));
    o.y = fast_exp2(scale * (acc[r][1] + bvv.y));
    o.z = fast_exp2(scale * (acc[r][2] + bvv.z));
    o.w = fast_exp2(scale * (acc[r][3] + bvv.w));
    *(float4*)(out + (size_t)(row0 + (ty << 2) + r) * DD + bn + (tx << 2)) = o;
  }
}

// ---------------------------------------------------------------------------
// Fused score + softmax + context + concat + transposed alignment.
// Round-14 structure (512 blocks x 1024 threads, 4 q-rows, lane = (jj,dq),
// barrier-free score loop, software pipeline) with the ONE fix:
// __launch_bounds__(1024, 4) — VGPR cap 128, NO allocator squeeze.
// Rounds 10/14 proved: asking for occupancy (min-waves=8) forces 32 VGPRs
// and ~25 MB of scratch spill. Rounds 11/13 proved: with headroom the
// compiler lands 40-52 VGPRs naturally, <= 64 -> HW itself co-schedules
// 2 blocks/CU x 16 waves = 32 waves/CU. LDS 20.9 KB (not limiting).
// Math (Eq,Ev; x = Eq*Ev): quad-rcp; score = 256 - 2*S; min-S softmax.
// ---------------------------------------------------------------------------
__global__ __launch_bounds__(1024, 4) void attn_kernel(
    const float* __restrict__ qp, const float* __restrict__ vp,
    const float* __restrict__ value, const float* __restrict__ query,
    float* __restrict__ out1, float* __restrict__ out2) {
  __shared__ float qs[4 * 256];    // Eq rows, 4 KB
  __shared__ float alg[4 * ALGS];  // raw S then alignment, 8.3 KB
  __shared__ float part[2048];     // context partials, 8 KB

  const int t    = threadIdx.x;
  const int lane = t & 63;
  const int wv   = t >> 6;        // 0..15
  const int jj   = lane >> 2;     // 0..15
  const int dq   = lane & 3;      // d-quarter phase
  const int bb   = blockIdx.x & 7;          // batch -> XCD locality
  const int i0   = (blockIdx.x >> 3) << 2;  // first of 4 q-rows

  const float* vpb = vp + (size_t)bb * TV * DD;
  const float* qb  = qp + (size_t)(bb * TQ + i0) * DD;

  // stage 4 Eq rows into LDS (coalesced)
  if (t < 256) {
    const int qi = t >> 6, qc = (t & 63) << 2;
    *(float4*)&qs[qi * 256 + qc] = *(const float4*)(qb + (size_t)qi * DD + qc);
  }
  __syncthreads();

  // per-lane Ev row bases: j(jg) = jg*256 + wv*16 + jj
  const int jb = (wv << 4) + jj;       // 0..255
  const float* vr0 = vpb + (size_t)jb * DD + (dq << 2);
  const float* vr1 = vr0 + 256 * DD;
  const float* qlane = qs + (dq << 2);

  float acc[4][2] = {{0.f,0.f},{0.f,0.f},{0.f,0.f},{0.f,0.f}};

  // prime the pipeline: k = 0 operands
  float4 vn0 = *(const float4*)(vr0);
  float4 vn1 = *(const float4*)(vr1);
  float4 qn0 = *(const float4*)(qlane + 0 * 256);
  float4 qn1 = *(const float4*)(qlane + 1 * 256);
  float4 qn2 = *(const float4*)(qlane + 2 * 256);
  float4 qn3 = *(const float4*)(qlane + 3 * 256);

#pragma unroll 1
  for (int k = 0; k < 16; ++k) {
    float4 vc0 = vn0, vc1 = vn1;
    float4 q0 = qn0, q1 = qn1, q2 = qn2, q3 = qn3;
    if (k < 15) {  // issue k+1 loads BEFORE computing k
      const int dn = (k + 1) << 4;
      vn0 = *(const float4*)(vr0 + dn);
      vn1 = *(const float4*)(vr1 + dn);
      qn0 = *(const float4*)(qlane + 0 * 256 + dn);
      qn1 = *(const float4*)(qlane + 1 * 256 + dn);
      qn2 = *(const float4*)(qlane + 2 * 256 + dn);
      qn3 = *(const float4*)(qlane + 3 * 256 + dn);
    }
#pragma unroll
    for (int jg = 0; jg < 2; ++jg) {
      const float4 v4 = (jg == 0) ? vc0 : vc1;
#pragma unroll
      for (int i = 0; i < 4; ++i) {
        const float4 q4 = (i == 0) ? q0 : (i == 1) ? q1 : (i == 2) ? q2 : q3;
        float a = q4.x * v4.x, b = q4.y * v4.y;
        float c = q4.z * v4.z, d = q4.w * v4.w;
        float sab = a + b,  scd = c + d;
        float Q1 = fmaf(a, b, sab + 1.f);   // (1+a)(1+b)
        float Q2 = fmaf(c, d, scd + 1.f);   // (1+c)(1+d)
        float N  = fmaf(scd + 2.f, Q1, (sab + 2.f) * Q2);
        acc[i][jg] = fmaf(N, fast_rcp(Q1 * Q2), acc[i][jg]);
      }
    }
  }

  // quad butterfly (once): combine the 4 d-quarter partials within each jj
#pragma unroll
  for (int i = 0; i < 4; ++i)
#pragma unroll
    for (int jg = 0; jg < 2; ++jg) {
      acc[i][jg] += __shfl_xor(acc[i][jg], 1, 64);
      acc[i][jg] += __shfl_xor(acc[i][jg], 2, 64);
    }
  // lane writes the i = dq slice (banks <=2-way = free)
#pragma unroll
  for (int jg = 0; jg < 2; ++jg) {
    float x = (dq == 0) ? acc[0][jg] : (dq == 1) ? acc[1][jg]
            : (dq == 2) ? acc[2][jg] : acc[3][jg];
    alg[dq * ALGS + (jg << 8) + jb] = x;
  }
  __syncthreads();

  // ---- softmax over j: wave wv (<4) owns row wv exclusively ----
  // score = 256 - 2*S -> max(score) <-> min(S); w = exp2(CC*(Smin - S))
  if (wv < 4) {
    float s[8];
#pragma unroll
    for (int c = 0; c < 8; ++c) s[c] = alg[wv * ALGS + (c << 6) + lane];
    float mn = s[0];
#pragma unroll
    for (int c = 1; c < 8; ++c) mn = fminf(mn, s[c]);
#pragma unroll
    for (int m = 1; m < 64; m <<= 1) mn = fminf(mn, __shfl_xor(mn, m, 64));

    const float CC = 2.8853900817779268f;  // 2*log2(e)
    float p[8];
    float sum = 0.f;
#pragma unroll
    for (int c = 0; c < 8; ++c) { p[c] = fast_exp2(CC * (mn - s[c])); sum += p[c]; }
#pragma unroll
    for (int m = 1; m < 64; m <<= 1) sum += __shfl_xor(sum, m, 64);
    const float inv = fast_rcp(sum);
#pragma unroll
    for (int c = 0; c < 8; ++c) alg[wv * ALGS + (c << 6) + lane] = p[c] * inv;
  }
  __syncthreads();

  // ---- alignment_t write: out2[b][j][i0..i0+3], threads 0..511 ----
  if (t < 512) {
    const int j = t;
    float4 av = make_float4(alg[j], alg[ALGS + j], alg[2 * ALGS + j], alg[3 * ALGS + j]);
    *(float4*)(out2 + (size_t)(bb * TV + j) * TQ + i0) = av;
  }

  // ---- context: thread (f = t&255, rp = (t>>8)&1, jh = t>>9) ----
  const int f  = t & 255;
  const int rp = (t >> 8) & 1;    // row-pair: rows 2rp, 2rp+1
  const int jh = t >> 9;          // j-half: [jh*256, jh*256+256)
  float c0 = 0.f, c1 = 0.f;
  const float* vb = value + (size_t)bb * TV * DD;
  const float* a0p = &alg[(2 * rp + 0) * ALGS];
  const float* a1p = &alg[(2 * rp + 1) * ALGS];
  const int jbeg = jh << 8;
#pragma unroll 4
  for (int j = jbeg; j < jbeg + 256; j += 4) {
    float v0 = vb[(size_t)(j + 0) * DD + f];
    float v1 = vb[(size_t)(j + 1) * DD + f];
    float v2 = vb[(size_t)(j + 2) * DD + f];
    float v3 = vb[(size_t)(j + 3) * DD + f];
    float4 a0 = *(const float4*)&a0p[j];
    float4 a1 = *(const float4*)&a1p[j];
    c0 += a0.x * v0 + a0.y * v1 + a0.z * v2 + a0.w * v3;
    c1 += a1.x * v0 + a1.y * v1 + a1.z * v2 + a1.w * v3;
  }
  part[(jh << 10) + (rp << 9) + f]       = c0;  // [jh][rp][row 2rp  ][f]
  part[(jh << 10) + (rp << 9) + 256 + f] = c1;  // [jh][rp][row 2rp+1][f]
  __syncthreads();

  // ---- combine halves + write [ctx | query]: thread -> (row = t>>8, f) ----
  {
    const int row = t >> 8;  // 0..3
    const int rpp = row >> 1, rw = row & 1;
    const float cfull = part[(rpp << 9) + (rw << 8) + f]
                      + part[1024 + (rpp << 9) + (rw << 8) + f];
    const float* qg = query + (size_t)(bb * TQ + i0) * DD;
    float* o = out1 + (size_t)(bb * TQ + i0) * (2 * DD);
    o[row * 512 + f]       = cfull;
    o[row * 512 + 256 + f] = qg[row * DD + f];
  }
}

// ---------------------------------------------------------------------------
extern "C" void kernel_launch(void* const* d_in, const int* in_sizes, int n_in,
                              void* d_out, int out_size, void* d_ws, size_t ws_size,
                              hipStream_t stream) {
  const float* query = (const float*)d_in[0];  // [8,256,256]
  const float* value = (const float*)d_in[1];  // [8,512,256]
  const float* W1    = (const float*)d_in[2];  // [256,256]
  const float* b1    = (const float*)d_in[3];  // [256]
  const float* W2    = (const float*)d_in[4];  // [256,256]
  const float* b2    = (const float*)d_in[5];  // [256]

  float* out1 = (float*)d_out;                     // context concat [8,256,512]
  float* out2 = out1 + (size_t)B_ * TQ * 2 * DD;   // alignment_t   [8,512,256]

  float* qp = (float*)d_ws;                        // Eq: 2048*256 floats
  float* vp = qp + (size_t)B_ * TQ * DD;           // Ev: 4096*256 floats

  const float SC = 2.8853900817779268f;  // 2*log2(e): exp(2x) = exp2(SC*x)

  proj_fused<<<dim3(96, 4), 256, 0, stream>>>(query, value, W1, b1, W2, b2, qp, vp, SC);
  attn_kernel<<<dim3(B_ * (TQ / 4)), 1024, 0, stream>>>(qp, vp, value, query, out1, out2);
}

// Round 16
// 138.572 us; speedup vs baseline: 1.1518x; 1.0215x over previous
//
#include <hip/hip_runtime.h>

#define B_  8
#define TQ  256
#define TV  512
#define DD  256
#define ALGS 520  // alg row stride: write banks <=2-way aliased = free

typedef float v2f __attribute__((ext_vector_type(2)));

__device__ __forceinline__ float fast_exp2(float x) {
#if __has_builtin(__builtin_amdgcn_exp2f)
  return __builtin_amdgcn_exp2f(x);
#else
  return __exp2f(x);
#endif
}
__device__ __forceinline__ float fast_rcp(float x) {
#if __has_builtin(__builtin_amdgcn_rcpf)
  return __builtin_amdgcn_rcpf(x);
#else
  return 1.0f / x;
#endif
}
__device__ __forceinline__ v2f v2fma(v2f a, v2f b, v2f c) {
#if __has_builtin(__builtin_elementwise_fma)
  return __builtin_elementwise_fma(a, b, c);
#else
  v2f r; r.x = fmaf(a.x, b.x, c.x); r.y = fmaf(a.y, b.y, c.y); return r;
#endif
}

// ---------------------------------------------------------------------------
// Fused projections with EXP epilogue (identical to rounds 8-15 — validated):
//   Eq = exp2(SC*(query@W1 + b1)),  Ev = exp2(SC*(value@W2 + b2))
// ---------------------------------------------------------------------------
__global__ __launch_bounds__(256) void proj_fused(
    const float* __restrict__ query, const float* __restrict__ value,
    const float* __restrict__ W1, const float* __restrict__ b1,
    const float* __restrict__ W2, const float* __restrict__ b2,
    float* __restrict__ qp, float* __restrict__ vp, float scale) {
  __shared__ float As[2][32][64];  // [p][k][m ^ sw(k)]
  __shared__ float Bs[2][32][64];  // [p][k][n]
  const int t  = threadIdx.x;
  const int rt = blockIdx.x;
  const int bn = blockIdx.y << 6;

  const float* A; const float* W; const float* bias; float* out; int row0;
  if (rt < 32) { row0 = rt << 6;        A = query; W = W1; bias = b1; out = qp; }
  else         { row0 = (rt - 32) << 6; A = value; W = W2; bias = b2; out = vp; }

  const int tx = t & 15, ty = t >> 4;
  const int aar = t >> 3, aac = (t & 7) << 2;
  const int bbr = t >> 4, bbc = (t & 15) << 2;

  float4 ra[2], rb[2];
#pragma unroll
  for (int it = 0; it < 2; ++it) {
    ra[it] = *(const float4*)(A + (size_t)(row0 + (it << 5) + aar) * DD + aac);
    rb[it] = *(const float4*)(W + (size_t)((it << 4) + bbr) * DD + bn + bbc);
  }
#pragma unroll
  for (int it = 0; it < 2; ++it) {
    const int m = (it << 5) + aar;
#pragma unroll
    for (int c = 0; c < 4; ++c) {
      const int k = aac + c;
      As[0][k][m ^ (((k >> 2) & 7) << 2)] = (&ra[it].x)[c];
    }
    *(float4*)&Bs[0][(it << 4) + bbr][bbc] = rb[it];
  }
  __syncthreads();

  float acc[4][4] = {{0.f,0.f,0.f,0.f},{0.f,0.f,0.f,0.f},
                     {0.f,0.f,0.f,0.f},{0.f,0.f,0.f,0.f}};
  int p = 0;

  for (int k0 = 0; k0 < 256; k0 += 32) {
    const bool more = (k0 + 32) < 256;
    if (more) {
#pragma unroll
      for (int it = 0; it < 2; ++it) {
        ra[it] = *(const float4*)(A + (size_t)(row0 + (it << 5) + aar) * DD + k0 + 32 + aac);
        rb[it] = *(const float4*)(W + (size_t)(k0 + 32 + (it << 4) + bbr) * DD + bn + bbc);
      }
    }
#pragma unroll
    for (int k = 0; k < 32; ++k) {
      float4 aq = *(const float4*)&As[p][k][(ty << 2) ^ (((k >> 2) & 7) << 2)];
      float4 bq = *(const float4*)&Bs[p][k][tx << 2];
      acc[0][0] = fmaf(aq.x, bq.x, acc[0][0]); acc[0][1] = fmaf(aq.x, bq.y, acc[0][1]);
      acc[0][2] = fmaf(aq.x, bq.z, acc[0][2]); acc[0][3] = fmaf(aq.x, bq.w, acc[0][3]);
      acc[1][0] = fmaf(aq.y, bq.x, acc[1][0]); acc[1][1] = fmaf(aq.y, bq.y, acc[1][1]);
      acc[1][2] = fmaf(aq.y, bq.z, acc[1][2]); acc[1][3] = fmaf(aq.y, bq.w, acc[1][3]);
      acc[2][0] = fmaf(aq.z, bq.x, acc[2][0]); acc[2][1] = fmaf(aq.z, bq.y, acc[2][1]);
      acc[2][2] = fmaf(aq.z, bq.z, acc[2][2]); acc[2][3] = fmaf(aq.z, bq.w, acc[2][3]);
      acc[3][0] = fmaf(aq.w, bq.x, acc[3][0]); acc[3][1] = fmaf(aq.w, bq.y, acc[3][1]);
      acc[3][2] = fmaf(aq.w, bq.z, acc[3][2]); acc[3][3] = fmaf(aq.w, bq.w, acc[3][3]);
    }
    if (more) {
      const int q = p ^ 1;
#pragma unroll
      for (int it = 0; it < 2; ++it) {
        const int m = (it << 5) + aar;
#pragma unroll
        for (int c = 0; c < 4; ++c) {
          const int k = aac + c;
          As[q][k][m ^ (((k >> 2) & 7) << 2)] = (&ra[it].x)[c];
        }
        *(float4*)&Bs[q][(it << 4) + bbr][bbc] = rb[it];
      }
      __syncthreads();
      p = q;
    }
  }

  float4 bvv = *(const float4*)&bias[bn + (tx << 2)];
#pragma unroll
  for (int r = 0; r < 4; ++r) {
    float4 o;
    o.x = fast_exp2(scale * (acc[r][0] + bvv.x));
    o.y = fast_exp2(scale * (acc[r][1] + bvv.y));
    o.z = fast_exp2(scale * (acc[r][2] + bvv.z));
    o.w = fast_exp2(scale * (acc[r][3] + bvv.w));
    *(float4*)(out + (size_t)(row0 + (ty << 2) + r) * DD + bn + (tx << 2)) = o;
  }
}

// ---------------------------------------------------------------------------
// Fused score + softmax + context + concat + transposed alignment.
// Round-13 structure byte-for-byte (best measured: 512 blocks x 512 thr,
// 4 q-rows, lane = (jj,dq), barrier-free score loop, software pipeline,
// __launch_bounds__(512,4)) with ONE change: the inner quad-rcp math uses
// PACKED FP32 (v_pk_mul/add/fma via float2 ext-vectors). Pairs are
// (d0,d2),(d1,d3) so the packed lanes are the natural lo/hi halves of the
// loaded float4s — zero shuffle cost. Per 4 elems: 6 packed + 4 scalar
// + 1 rcp = 28 issue cy (was 16 scalar + 1 rcp = 40 cy) -> 1.43x on the
// score phase, which round 15 showed is issue-bound, not occupancy-bound.
// Math: 1/(1+x0)+1/(1+x2) = (2+s)/((1+x0)(1+x2)), s=x0+x2; quad-combine
// over common denominator; score = 256 - 2*S; min-S softmax.
// ---------------------------------------------------------------------------
__global__ __launch_bounds__(512, 4) void attn_kernel(
    const float* __restrict__ qp, const float* __restrict__ vp,
    const float* __restrict__ value, const float* __restrict__ query,
    float* __restrict__ out1, float* __restrict__ out2) {
  __shared__ float qs[4 * 256];    // Eq rows, 4 KB
  __shared__ float alg[4 * ALGS];  // raw S then alignment, 8.3 KB

  const int t    = threadIdx.x;
  const int lane = t & 63;
  const int wv   = t >> 6;        // 0..7
  const int jj   = lane >> 2;     // 0..15: row within wave's 16-row group
  const int dq   = lane & 3;      // d-quarter phase
  const int bb   = blockIdx.x & 7;          // batch -> XCD locality
  const int i0   = (blockIdx.x >> 3) << 2;  // first of 4 q-rows

  const float* vpb = vp + (size_t)bb * TV * DD;
  const float* qb  = qp + (size_t)(bb * TQ + i0) * DD;

  // stage 4 Eq rows into LDS (coalesced)
  if (t < 256) {
    const int qi = t >> 6, qc = (t & 63) << 2;
    *(float4*)&qs[qi * 256 + qc] = *(const float4*)(qb + (size_t)qi * DD + qc);
  }
  __syncthreads();

  // per-lane Ev row bases: j(jg) = jg*128 + wv*16 + jj
  const int jb = (wv << 4) + jj;
  const float* vr0 = vpb + (size_t)jb * DD + (dq << 2);
  const float* vr1 = vr0 + 128 * DD;
  const float* vr2 = vr0 + 256 * DD;
  const float* vr3 = vr0 + 384 * DD;
  const float* qlane = qs + (dq << 2);

  float acc[4][4] = {{0.f,0.f,0.f,0.f},{0.f,0.f,0.f,0.f},
                     {0.f,0.f,0.f,0.f},{0.f,0.f,0.f,0.f}};

  // prime the pipeline: k = 0 operands
  float4 vn0 = *(const float4*)(vr0);
  float4 vn1 = *(const float4*)(vr1);
  float4 vn2 = *(const float4*)(vr2);
  float4 vn3 = *(const float4*)(vr3);
  float4 qn0 = *(const float4*)(qlane + 0 * 256);
  float4 qn1 = *(const float4*)(qlane + 1 * 256);
  float4 qn2 = *(const float4*)(qlane + 2 * 256);
  float4 qn3 = *(const float4*)(qlane + 3 * 256);

#pragma unroll 1
  for (int k = 0; k < 16; ++k) {
    // rotate pipeline regs
    float4 vc0 = vn0, vc1 = vn1, vc2 = vn2, vc3 = vn3;
    float4 q0 = qn0, q1 = qn1, q2 = qn2, q3 = qn3;
    if (k < 15) {  // issue k+1 loads BEFORE computing k
      const int dn = (k + 1) << 4;
      vn0 = *(const float4*)(vr0 + dn);
      vn1 = *(const float4*)(vr1 + dn);
      vn2 = *(const float4*)(vr2 + dn);
      vn3 = *(const float4*)(vr3 + dn);
      qn0 = *(const float4*)(qlane + 0 * 256 + dn);
      qn1 = *(const float4*)(qlane + 1 * 256 + dn);
      qn2 = *(const float4*)(qlane + 2 * 256 + dn);
      qn3 = *(const float4*)(qlane + 3 * 256 + dn);
    }
#pragma unroll
    for (int jg = 0; jg < 4; ++jg) {
      const float4 v4 = (jg == 0) ? vc0 : (jg == 1) ? vc1 : (jg == 2) ? vc2 : vc3;
      const v2f vlo = {v4.x, v4.y};
      const v2f vhi = {v4.z, v4.w};
#pragma unroll
      for (int i = 0; i < 4; ++i) {
        const float4 q4 = (i == 0) ? q0 : (i == 1) ? q1 : (i == 2) ? q2 : q3;
        v2f X = (v2f){q4.x, q4.y} * vlo;   // pk_mul: {x0, x1}
        v2f Y = (v2f){q4.z, q4.w} * vhi;   // pk_mul: {x2, x3}
        v2f s = X + Y;                      // pk_add: pair sums (d0,d2),(d1,d3)
        v2f Q = v2fma(X, Y, s + 1.0f);      // pk_add + pk_fma: {(1+x0)(1+x2), (1+x1)(1+x3)}
        v2f N = s + 2.0f;                   // pk_add
        float Nq = fmaf(N.x, Q.y, N.y * Q.x);
        acc[i][jg] = fmaf(Nq, fast_rcp(Q.x * Q.y), acc[i][jg]);
      }
    }
  }

  // quad butterfly (once): combine the 4 d-quarter partials within each jj
#pragma unroll
  for (int i = 0; i < 4; ++i)
#pragma unroll
    for (int jg = 0; jg < 4; ++jg) {
      acc[i][jg] += __shfl_xor(acc[i][jg], 1, 64);
      acc[i][jg] += __shfl_xor(acc[i][jg], 2, 64);
    }
  // lane writes the i = dq slice (banks <=2-way with ALGS=520)
#pragma unroll
  for (int jg = 0; jg < 4; ++jg) {
    float x = (dq == 0) ? acc[0][jg] : (dq == 1) ? acc[1][jg]
            : (dq == 2) ? acc[2][jg] : acc[3][jg];
    alg[dq * ALGS + (jg << 7) + jb] = x;
  }
  __syncthreads();

  // ---- softmax over j: wave wv (<4) owns row wv exclusively ----
  // score = 256 - 2*S -> max(score) <-> min(S); w = exp2(CC*(Smin - S))
  if (wv < 4) {
    float s[8];
#pragma unroll
    for (int c = 0; c < 8; ++c) s[c] = alg[wv * ALGS + (c << 6) + lane];
    float mn = s[0];
#pragma unroll
    for (int c = 1; c < 8; ++c) mn = fminf(mn, s[c]);
#pragma unroll
    for (int m = 1; m < 64; m <<= 1) mn = fminf(mn, __shfl_xor(mn, m, 64));

    const float CC = 2.8853900817779268f;  // 2*log2(e)
    float p[8];
    float sum = 0.f;
#pragma unroll
    for (int c = 0; c < 8; ++c) { p[c] = fast_exp2(CC * (mn - s[c])); sum += p[c]; }
#pragma unroll
    for (int m = 1; m < 64; m <<= 1) sum += __shfl_xor(sum, m, 64);
    const float inv = fast_rcp(sum);
#pragma unroll
    for (int c = 0; c < 8; ++c) alg[wv * ALGS + (c << 6) + lane] = p[c] * inv;
  }
  __syncthreads();

  // ---- alignment_t write: out2[b][j][i0..i0+3], one float4 per thread ----
  {
    const int j = t;  // 0..511
    float4 av = make_float4(alg[j], alg[ALGS + j], alg[2 * ALGS + j], alg[3 * ALGS + j]);
    *(float4*)(out2 + (size_t)(bb * TV + j) * TQ + i0) = av;
  }

  // ---- context: thread t owns (feature f, row-pair rp) ----
  const int f  = t & 255;
  const int rp = t >> 8;          // 0 or 1 -> rows 2rp, 2rp+1
  float c0 = 0.f, c1 = 0.f;
  const float* vb = value + (size_t)bb * TV * DD;
  const float* a0p = &alg[(2 * rp + 0) * ALGS];
  const float* a1p = &alg[(2 * rp + 1) * ALGS];
#pragma unroll 4
  for (int j = 0; j < TV; j += 4) {
    float v0 = vb[(size_t)(j + 0) * DD + f];
    float v1 = vb[(size_t)(j + 1) * DD + f];
    float v2 = vb[(size_t)(j + 2) * DD + f];
    float v3 = vb[(size_t)(j + 3) * DD + f];
    float4 a0 = *(const float4*)&a0p[j];
    float4 a1 = *(const float4*)&a1p[j];
    c0 += a0.x * v0 + a0.y * v1 + a0.z * v2 + a0.w * v3;
    c1 += a1.x * v0 + a1.y * v1 + a1.z * v2 + a1.w * v3;
  }

  // ---- context-concat output: [ctx | query] per row ----
  const int r0_ = (rp << 1), r1_ = r0_ + 1;
  const float* qg = query + (size_t)(bb * TQ + i0) * DD;
  float* o = out1 + (size_t)(bb * TQ + i0) * (2 * DD);
  o[r0_ * 512 + f] = c0; o[r0_ * 512 + 256 + f] = qg[r0_ * DD + f];
  o[r1_ * 512 + f] = c1; o[r1_ * 512 + 256 + f] = qg[r1_ * DD + f];
}

// ---------------------------------------------------------------------------
extern "C" void kernel_launch(void* const* d_in, const int* in_sizes, int n_in,
                              void* d_out, int out_size, void* d_ws, size_t ws_size,
                              hipStream_t stream) {
  const float* query = (const float*)d_in[0];  // [8,256,256]
  const float* value = (const float*)d_in[1];  // [8,512,256]
  const float* W1    = (const float*)d_in[2];  // [256,256]
  const float* b1    = (const float*)d_in[3];  // [256]
  const float* W2    = (const float*)d_in[4];  // [256,256]
  const float* b2    = (const float*)d_in[5];  // [256]

  float* out1 = (float*)d_out;                     // context concat [8,256,512]
  float* out2 = out1 + (size_t)B_ * TQ * 2 * DD;   // alignment_t   [8,512,256]

  float* qp = (float*)d_ws;                        // Eq: 2048*256 floats
  float* vp = qp + (size_t)B_ * TQ * DD;           // Ev: 4096*256 floats

  const float SC = 2.8853900817779268f;  // 2*log2(e): exp(2x) = exp2(SC*x)

  proj_fused<<<dim3(96, 4), 256, 0, stream>>>(query, value, W1, b1, W2, b2, qp, vp, SC);
  attn_kernel<<<dim3(B_ * (TQ / 4)), 512, 0, stream>>>(qp, vp, value, query, out1, out2);
}